// Round 1
// baseline (1360.401 us; speedup 1.0000x reference)
//
#include <hip/hip_runtime.h>
#include <hip/hip_bf16.h>

#define CH 32

// K1: layer-1 scalar edge aggregation: s1[dst] += x[src]*w
__global__ void edge_scalar_kernel(const int* __restrict__ src, const int* __restrict__ dst,
                                   const float* __restrict__ w, const float* __restrict__ x,
                                   float* __restrict__ s1, int E) {
    int e = blockIdx.x * blockDim.x + threadIdx.x;
    if (e < E) {
        atomicAdd(&s1[dst[e]], x[src[e]] * w[e]);
    }
}

// K2: layer-1 output: x1[i,c] = relu(s1[i]*W11[c] + x[i]*W21[c] + b1[c])
__global__ void layer1_out_kernel(const float* __restrict__ x, const float* __restrict__ s1,
                                  const float* __restrict__ W11, const float* __restrict__ W21,
                                  const float* __restrict__ b1, float* __restrict__ x1, int N) {
    int i = blockIdx.x * blockDim.x + threadIdx.x;
    int node = i >> 5, c = i & 31;
    if (node < N) {
        x1[i] = fmaxf(fmaf(s1[node], W11[c], fmaf(x[node], W21[c], b1[c])), 0.f);
    }
}

// K3: per-node GEMMs: h = relu?(xin) @ W1 ; agg = relu?(xin) @ W2 + b
template <bool RELU_IN>
__global__ void gemm_init_kernel(const float* __restrict__ xin,
                                 const float* __restrict__ W1, const float* __restrict__ W2,
                                 const float* __restrict__ b,
                                 float* __restrict__ h, float* __restrict__ agg, int N) {
    __shared__ float w1s[CH][CH];
    __shared__ float w2s[CH][CH];
    __shared__ float xs[8][CH];
    int tid = threadIdx.x;  // 256
    for (int t = tid; t < CH * CH; t += 256) {
        w1s[t >> 5][t & 31] = W1[t];
        w2s[t >> 5][t & 31] = W2[t];
    }
    int ln = tid >> 5, c = tid & 31;
    int node = blockIdx.x * 8 + ln;
    float xv = 0.f;
    if (node < N) {
        xv = xin[node * CH + c];
        if (RELU_IN) xv = fmaxf(xv, 0.f);
    }
    xs[ln][c] = xv;
    __syncthreads();
    float a1 = 0.f;
    float a2 = b[c];
#pragma unroll
    for (int k = 0; k < CH; k++) {
        float xk = xs[ln][k];
        a1 = fmaf(xk, w1s[k][c], a1);
        a2 = fmaf(xk, w2s[k][c], a2);
    }
    if (node < N) {
        h[node * CH + c] = a1;
        agg[node * CH + c] = a2;
    }
}

// K4: wide edge scatter: agg[dst,c] += h[src,c]*w   (thread per (edge, channel))
__global__ void edge_scatter_kernel(const int* __restrict__ src, const int* __restrict__ dst,
                                    const float* __restrict__ w, const float* __restrict__ h,
                                    float* __restrict__ agg, int E) {
    int t = blockIdx.x * blockDim.x + threadIdx.x;
    int e = t >> 5, c = t & 31;
    if (e < E) {
        float val = h[src[e] * CH + c] * w[e];
        atomicAdd(&agg[dst[e] * CH + c], val);
    }
}

// K5: pooling: sums[seg[i],c] += relu(x3[i,c]); counts[seg[i]] += 1
__global__ void pool_kernel(const float* __restrict__ x3, const int* __restrict__ seg,
                            float* __restrict__ sums, float* __restrict__ counts, int N) {
    int i = blockIdx.x * blockDim.x + threadIdx.x;
    int node = i >> 5, c = i & 31;
    if (node < N) {
        int g = seg[node];
        atomicAdd(&sums[g * CH + c], fmaxf(x3[i], 0.f));
        if (c == 0) atomicAdd(&counts[g], 1.f);
    }
}

// K6: head: out[g] = sigmoid(dot(sums[g]/max(counts,1), Wd) + bd)
__global__ void head_kernel(const float* __restrict__ sums, const float* __restrict__ counts,
                            const float* __restrict__ Wd, const float* __restrict__ bd,
                            float* __restrict__ out, int G) {
    int g = blockIdx.x * blockDim.x + threadIdx.x;
    if (g < G) {
        float inv_cnt = 1.f / fmaxf(counts[g], 1.f);
        float acc = bd[0];
#pragma unroll
        for (int c = 0; c < CH; c++) {
            acc = fmaf(sums[g * CH + c] * inv_cnt, Wd[c], acc);
        }
        out[g] = 1.f / (1.f + expf(-acc));
    }
}

extern "C" void kernel_launch(void* const* d_in, const int* in_sizes, int n_in,
                              void* d_out, int out_size, void* d_ws, size_t ws_size,
                              hipStream_t stream) {
    const float* x        = (const float*)d_in[0];
    const int*   edge_src = (const int*)d_in[1];
    const int*   edge_dst = (const int*)d_in[2];
    const float* edge_w   = (const float*)d_in[3];
    const int*   seg      = (const int*)d_in[4];
    const float* W1_1 = (const float*)d_in[5];
    const float* W2_1 = (const float*)d_in[6];
    const float* b1   = (const float*)d_in[7];
    const float* W1_2 = (const float*)d_in[8];
    const float* W2_2 = (const float*)d_in[9];
    const float* b2   = (const float*)d_in[10];
    const float* W1_3 = (const float*)d_in[11];
    const float* W2_3 = (const float*)d_in[12];
    const float* b3   = (const float*)d_in[13];
    const float* Wd   = (const float*)d_in[14];
    const float* bd   = (const float*)d_in[15];
    float* out = (float*)d_out;

    const int N = in_sizes[0];   // 262144 (DIN=1)
    const int E = in_sizes[1];   // 4194304
    const int G = out_size;      // 4096

    const size_t NB = (size_t)N * CH;  // floats per node buffer
    float* bufA = (float*)d_ws;        // x1 -> h3 -> (sums/counts)
    float* bufB = bufA + NB;           // s1 -> h2 -> x3
    float* bufC = bufB + NB;           // x2
    (void)ws_size;

    float* s1 = bufB;                  // aliases bufB before layer-2 h is written there
    float* sums = bufA;                // aliases bufA after layer-3 h is dead
    float* counts = bufA + (size_t)G * CH;

    const int BLK = 256;

    // ---- Layer 1 ----
    hipMemsetAsync(s1, 0, (size_t)N * sizeof(float), stream);
    edge_scalar_kernel<<<(E + BLK - 1) / BLK, BLK, 0, stream>>>(edge_src, edge_dst, edge_w, x, s1, E);
    layer1_out_kernel<<<((size_t)N * CH + BLK - 1) / BLK, BLK, 0, stream>>>(x, s1, W1_1, W2_1, b1, bufA, N);
    // bufA = x1 (post-relu)

    // ---- Layer 2 ----  xin=bufA, h=bufB, agg(x2)=bufC
    gemm_init_kernel<false><<<(N + 7) / 8, BLK, 0, stream>>>(bufA, W1_2, W2_2, b2, bufB, bufC, N);
    edge_scatter_kernel<<<((size_t)E * CH + BLK - 1) / BLK, BLK, 0, stream>>>(edge_src, edge_dst, edge_w, bufB, bufC, E);
    // bufC = x2 (pre-relu)

    // ---- Layer 3 ----  xin=bufC (relu on read), h=bufA, agg(x3)=bufB
    gemm_init_kernel<true><<<(N + 7) / 8, BLK, 0, stream>>>(bufC, W1_3, W2_3, b3, bufA, bufB, N);
    edge_scatter_kernel<<<((size_t)E * CH + BLK - 1) / BLK, BLK, 0, stream>>>(edge_src, edge_dst, edge_w, bufA, bufB, E);
    // bufB = x3 (pre-relu)

    // ---- Pool + head ----  sums/counts in bufA (h3 dead now)
    hipMemsetAsync(sums, 0, (size_t)G * CH * sizeof(float), stream);
    hipMemsetAsync(counts, 0, (size_t)G * sizeof(float), stream);
    pool_kernel<<<((size_t)N * CH + BLK - 1) / BLK, BLK, 0, stream>>>(bufB, seg, sums, counts, N);
    head_kernel<<<(G + BLK - 1) / BLK, BLK, 0, stream>>>(sums, counts, Wd, bd, out, G);
}

// Round 2
// 944.710 us; speedup vs baseline: 1.4400x; 1.4400x over previous
//
#include <hip/hip_runtime.h>
#include <hip/hip_bf16.h>

#define CH 32

// ---------------- CSR build ----------------

// deg[dst[e]] += 1   (deg aliases `pos`)
__global__ void hist_kernel(const int* __restrict__ dst, int* __restrict__ deg, int E) {
    int e = blockIdx.x * blockDim.x + threadIdx.x;
    if (e < E) atomicAdd(&deg[dst[e]], 1);
}

// blockSums[b] = sum of deg[b*1024 .. b*1024+1023]
__global__ void scanA_kernel(const int* __restrict__ deg, int* __restrict__ blockSums, int N) {
    int tid = threadIdx.x;  // 256
    int base = blockIdx.x * 1024 + tid * 4;
    int s = 0;
    if (base + 3 < N) {
        int4 v = *reinterpret_cast<const int4*>(deg + base);
        s = v.x + v.y + v.z + v.w;
    } else {
        for (int k = 0; k < 4; k++) if (base + k < N) s += deg[base + k];
    }
    for (int m = 1; m < 64; m <<= 1) s += __shfl_xor(s, m);
    __shared__ int ws[4];
    if ((tid & 63) == 0) ws[tid >> 6] = s;
    __syncthreads();
    if (tid == 0) blockSums[blockIdx.x] = ws[0] + ws[1] + ws[2] + ws[3];
}

// exclusive scan of blockSums (nb <= 1024), single block of 1024 threads
__global__ void scanB_kernel(int* __restrict__ blockSums, int nb) {
    __shared__ int l[1024];
    int tid = threadIdx.x;
    int v = (tid < nb) ? blockSums[tid] : 0;
    l[tid] = v;
    __syncthreads();
    for (int off = 1; off < 1024; off <<= 1) {
        int t = (tid >= off) ? l[tid - off] : 0;
        __syncthreads();
        l[tid] += t;
        __syncthreads();
    }
    if (tid < nb) blockSums[tid] = l[tid] - v;  // exclusive
}

// row_start[i] = global exclusive prefix of deg; pos[i] = row_start[i]; row_start[N] = E
__global__ void scanC_kernel(int* __restrict__ degpos, const int* __restrict__ blockSums,
                             int* __restrict__ row_start, int N) {
    int tid = threadIdx.x;  // 256
    int base = blockIdx.x * 1024 + tid * 4;
    int d[4] = {0, 0, 0, 0};
    if (base + 3 < N) {
        int4 v = *reinterpret_cast<const int4*>(degpos + base);
        d[0] = v.x; d[1] = v.y; d[2] = v.z; d[3] = v.w;
    } else {
        for (int k = 0; k < 4; k++) if (base + k < N) d[k] = degpos[base + k];
    }
    int tsum = d[0] + d[1] + d[2] + d[3];
    __shared__ int l[256];
    l[tid] = tsum;
    __syncthreads();
    for (int off = 1; off < 256; off <<= 1) {
        int t = (tid >= off) ? l[tid - off] : 0;
        __syncthreads();
        l[tid] += t;
        __syncthreads();
    }
    int offset = blockSums[blockIdx.x] + l[tid] - tsum;
    for (int k = 0; k < 4; k++) {
        int i = base + k;
        if (i < N) {
            row_start[i] = offset;
            degpos[i] = offset;        // becomes `pos` for the scatter phase
            offset += d[k];
            if (i == N - 1) row_start[N] = offset;
        }
    }
}

// col[j]=src[e], wv[j]=w[e] at j = pos[dst[e]]++
__global__ void scatter_kernel(const int* __restrict__ src, const int* __restrict__ dst,
                               const float* __restrict__ w, int* __restrict__ pos,
                               int* __restrict__ col, float* __restrict__ wv, int E) {
    int e = blockIdx.x * blockDim.x + threadIdx.x;
    if (e < E) {
        int j = atomicAdd(&pos[dst[e]], 1);
        col[j] = src[e];
        wv[j] = w[e];
    }
}

// ---------------- Layer 1 (DIN=1, rank-1) fused: s=A_hat@x; x1=relu(s*W11 + x*W21 + b1); h2=x1@W1_2
__global__ void l1_fused_kernel(const float* __restrict__ x,
                                const int* __restrict__ row_start, const int* __restrict__ col,
                                const float* __restrict__ wv,
                                const float* __restrict__ W11, const float* __restrict__ W21,
                                const float* __restrict__ b1, const float* __restrict__ W12,
                                float* __restrict__ x1, float* __restrict__ h2, int N) {
    __shared__ float w1s[CH][CH];
    __shared__ float xs[8][CH];
    int tid = threadIdx.x;  // 256
    for (int t = tid; t < CH * CH; t += 256) w1s[t >> 5][t & 31] = W12[t];
    int ln = tid >> 5, c = tid & 31;
    int node = blockIdx.x * 8 + ln;
    float s = 0.f, xv = 0.f;
    if (node < N) {
        xv = x[node];
        int lo = row_start[node], hi = row_start[node + 1];
        for (int j = lo + c; j < hi; j += 32) s += wv[j] * x[col[j]];
    }
    for (int m = 1; m < 32; m <<= 1) s += __shfl_xor(s, m);  // within 32-lane half
    float x1v = 0.f;
    if (node < N) {
        x1v = fmaxf(fmaf(s, W11[c], fmaf(xv, W21[c], b1[c])), 0.f);
        x1[node * CH + c] = x1v;
    }
    xs[ln][c] = x1v;
    __syncthreads();
    if (node < N) {
        float a = 0.f;
#pragma unroll
        for (int k = 0; k < CH; k++) a = fmaf(xs[ln][k], w1s[k][c], a);
        h2[node * CH + c] = a;
    }
}

// h = xin @ W1
__global__ void gemm_h_kernel(const float* __restrict__ xin, const float* __restrict__ W1,
                              float* __restrict__ h, int N) {
    __shared__ float w1s[CH][CH];
    __shared__ float xs[8][CH];
    int tid = threadIdx.x;
    for (int t = tid; t < CH * CH; t += 256) w1s[t >> 5][t & 31] = W1[t];
    int ln = tid >> 5, c = tid & 31;
    int node = blockIdx.x * 8 + ln;
    float xv = (node < N) ? xin[node * CH + c] : 0.f;
    xs[ln][c] = xv;
    __syncthreads();
    if (node < N) {
        float a = 0.f;
#pragma unroll
        for (int k = 0; k < CH; k++) a = fmaf(xs[ln][k], w1s[k][c], a);
        h[node * CH + c] = a;
    }
}

// xio[i] = relu( sum_j wv*h[col] + xio[i]@W2 + b )   (in-place; gather-reduce, no atomics)
__global__ void gather_kernel(float* __restrict__ xio, const float* __restrict__ h,
                              const int* __restrict__ row_start, const int* __restrict__ col,
                              const float* __restrict__ wv, const float* __restrict__ W2,
                              const float* __restrict__ b, int N) {
    __shared__ float w2s[CH][CH];
    __shared__ float xs[8][CH];
    int tid = threadIdx.x;
    for (int t = tid; t < CH * CH; t += 256) w2s[t >> 5][t & 31] = W2[t];
    int ln = tid >> 5, c = tid & 31;
    int node = blockIdx.x * 8 + ln;
    float xv = (node < N) ? xio[node * CH + c] : 0.f;
    xs[ln][c] = xv;
    __syncthreads();
    if (node >= N) return;
    float acc = b[c];
#pragma unroll
    for (int k = 0; k < CH; k++) acc = fmaf(xs[ln][k], w2s[k][c], acc);
    int lo = row_start[node], hi = row_start[node + 1];
    int j = lo;
    for (; j + 2 <= hi; j += 2) {
        int s0 = col[j], s1 = col[j + 1];
        float w0 = wv[j], w1 = wv[j + 1];
        acc = fmaf(w0, h[s0 * CH + c], acc);
        acc = fmaf(w1, h[s1 * CH + c], acc);
    }
    if (j < hi) acc = fmaf(wv[j], h[col[j] * CH + c], acc);
    xio[node * CH + c] = fmaxf(acc, 0.f);
}

// seg is SORTED: one 64-thread block per graph; binary-search bounds; fused mean-pool + dense + sigmoid
__global__ void pool_head_kernel(const float* __restrict__ x3, const int* __restrict__ seg,
                                 const float* __restrict__ Wd, const float* __restrict__ bd,
                                 float* __restrict__ out, int N, int G) {
    int g = blockIdx.x;
    int tid = threadIdx.x;  // 64
    int lo = 0, hi = N;
    while (lo < hi) { int mid = (lo + hi) >> 1; if (seg[mid] < g) lo = mid + 1; else hi = mid; }
    int start = lo;
    hi = N;
    while (lo < hi) { int mid = (lo + hi) >> 1; if (seg[mid] < g + 1) lo = mid + 1; else hi = mid; }
    int end = lo;
    int half = tid >> 5, c = tid & 31;
    float s = 0.f;
    for (int n = start + half; n < end; n += 2) s += x3[n * CH + c];  // x3 already post-relu
    s += __shfl_xor(s, 32);
    float t = s * Wd[c];
    for (int m = 1; m < 32; m <<= 1) t += __shfl_xor(t, m);
    if (tid == 0) {
        float cnt = fmaxf((float)(end - start), 1.f);
        float logit = t / cnt + bd[0];
        out[g] = 1.f / (1.f + expf(-logit));
    }
}

extern "C" void kernel_launch(void* const* d_in, const int* in_sizes, int n_in,
                              void* d_out, int out_size, void* d_ws, size_t ws_size,
                              hipStream_t stream) {
    const float* x        = (const float*)d_in[0];
    const int*   edge_src = (const int*)d_in[1];
    const int*   edge_dst = (const int*)d_in[2];
    const float* edge_w   = (const float*)d_in[3];
    const int*   seg      = (const int*)d_in[4];
    const float* W1_1 = (const float*)d_in[5];
    const float* W2_1 = (const float*)d_in[6];
    const float* b1   = (const float*)d_in[7];
    const float* W1_2 = (const float*)d_in[8];
    const float* W2_2 = (const float*)d_in[9];
    const float* b2   = (const float*)d_in[10];
    const float* W1_3 = (const float*)d_in[11];
    const float* W2_3 = (const float*)d_in[12];
    const float* b3   = (const float*)d_in[13];
    const float* Wd   = (const float*)d_in[14];
    const float* bd   = (const float*)d_in[15];
    float* out = (float*)d_out;

    const int N = in_sizes[0];   // 262144
    const int E = in_sizes[1];   // 4194304
    const int G = out_size;      // 4096
    (void)ws_size; (void)n_in;

    const size_t NB = (size_t)N * CH;
    // ws layout (all 16B-aligned): xbuf | hbuf | row_start[N+4] | pos[N] | col[E] | wv[E] | blockSums[1024]
    float* xbuf      = (float*)d_ws;
    float* hbuf      = xbuf + NB;
    int*   row_start = (int*)(hbuf + NB);
    int*   pos       = row_start + (N + 4);   // also serves as deg
    int*   col       = pos + N;
    float* wv        = (float*)(col + E);
    int*   blockSums = (int*)(wv + E);

    const int BLK = 256;
    const int nb1024 = (N + 1023) / 1024;     // 256 scan blocks

    // ---- CSR build (dst-indexed) ----
    hipMemsetAsync(pos, 0, (size_t)N * sizeof(int), stream);
    hist_kernel<<<(E + BLK - 1) / BLK, BLK, 0, stream>>>(edge_dst, pos, E);
    scanA_kernel<<<nb1024, BLK, 0, stream>>>(pos, blockSums, N);
    scanB_kernel<<<1, 1024, 0, stream>>>(blockSums, nb1024);
    scanC_kernel<<<nb1024, BLK, 0, stream>>>(pos, blockSums, row_start, N);
    scatter_kernel<<<(E + BLK - 1) / BLK, BLK, 0, stream>>>(edge_src, edge_dst, edge_w, pos, col, wv, E);

    // ---- Layer 1 (fused: agg + out + h2 gemm) ----
    l1_fused_kernel<<<(N + 7) / 8, BLK, 0, stream>>>(x, row_start, col, wv,
                                                     W1_1, W2_1, b1, W1_2, xbuf, hbuf, N);
    // ---- Layer 2: x2 = relu(A@h2 + x1@W2_2 + b2), in place ----
    gather_kernel<<<(N + 7) / 8, BLK, 0, stream>>>(xbuf, hbuf, row_start, col, wv, W2_2, b2, N);
    // ---- Layer 3 ----
    gemm_h_kernel<<<(N + 7) / 8, BLK, 0, stream>>>(xbuf, W1_3, hbuf, N);
    gather_kernel<<<(N + 7) / 8, BLK, 0, stream>>>(xbuf, hbuf, row_start, col, wv, W2_3, b3, N);

    // ---- Fused pool + head (seg sorted -> binary search, no atomics) ----
    pool_head_kernel<<<G, 64, 0, stream>>>(xbuf, seg, Wd, bd, out, N, G);
}

// Round 3
// 924.541 us; speedup vs baseline: 1.4714x; 1.0218x over previous
//
#include <hip/hip_runtime.h>
#include <hip/hip_bf16.h>

#define CH 32

// ---------------- CSR build ----------------

// deg[dst[e]] += 1   (deg aliases `pos`)
__global__ void hist_kernel(const int* __restrict__ dst, int* __restrict__ deg, int E) {
    int e = blockIdx.x * blockDim.x + threadIdx.x;
    if (e < E) atomicAdd(&deg[dst[e]], 1);
}

// blockSums[b] = sum of deg[b*1024 .. b*1024+1023]
__global__ void scanA_kernel(const int* __restrict__ deg, int* __restrict__ blockSums, int N) {
    int tid = threadIdx.x;  // 256
    int base = blockIdx.x * 1024 + tid * 4;
    int s = 0;
    if (base + 3 < N) {
        int4 v = *reinterpret_cast<const int4*>(deg + base);
        s = v.x + v.y + v.z + v.w;
    } else {
        for (int k = 0; k < 4; k++) if (base + k < N) s += deg[base + k];
    }
    for (int m = 1; m < 64; m <<= 1) s += __shfl_xor(s, m);
    __shared__ int ws[4];
    if ((tid & 63) == 0) ws[tid >> 6] = s;
    __syncthreads();
    if (tid == 0) blockSums[blockIdx.x] = ws[0] + ws[1] + ws[2] + ws[3];
}

// exclusive scan of blockSums (nb <= 1024), single block of 1024 threads
__global__ void scanB_kernel(int* __restrict__ blockSums, int nb) {
    __shared__ int l[1024];
    int tid = threadIdx.x;
    int v = (tid < nb) ? blockSums[tid] : 0;
    l[tid] = v;
    __syncthreads();
    for (int off = 1; off < 1024; off <<= 1) {
        int t = (tid >= off) ? l[tid - off] : 0;
        __syncthreads();
        l[tid] += t;
        __syncthreads();
    }
    if (tid < nb) blockSums[tid] = l[tid] - v;  // exclusive
}

// row_start[i] = global exclusive prefix of deg; pos[i] = row_start[i]; row_start[N] = E
__global__ void scanC_kernel(int* __restrict__ degpos, const int* __restrict__ blockSums,
                             int* __restrict__ row_start, int N) {
    int tid = threadIdx.x;  // 256
    int base = blockIdx.x * 1024 + tid * 4;
    int d[4] = {0, 0, 0, 0};
    if (base + 3 < N) {
        int4 v = *reinterpret_cast<const int4*>(degpos + base);
        d[0] = v.x; d[1] = v.y; d[2] = v.z; d[3] = v.w;
    } else {
        for (int k = 0; k < 4; k++) if (base + k < N) d[k] = degpos[base + k];
    }
    int tsum = d[0] + d[1] + d[2] + d[3];
    __shared__ int l[256];
    l[tid] = tsum;
    __syncthreads();
    for (int off = 1; off < 256; off <<= 1) {
        int t = (tid >= off) ? l[tid - off] : 0;
        __syncthreads();
        l[tid] += t;
        __syncthreads();
    }
    int offset = blockSums[blockIdx.x] + l[tid] - tsum;
    for (int k = 0; k < 4; k++) {
        int i = base + k;
        if (i < N) {
            row_start[i] = offset;
            degpos[i] = offset;        // becomes `pos` for the scatter phase
            offset += d[k];
            if (i == N - 1) row_start[N] = offset;
        }
    }
}

// colw[j] = {src[e], bits(w[e])} at j = pos[dst[e]]++   (single 8B packed store)
__global__ void scatter_kernel(const int* __restrict__ src, const int* __restrict__ dst,
                               const float* __restrict__ w, int* __restrict__ pos,
                               int2* __restrict__ colw, int E) {
    int e = blockIdx.x * blockDim.x + threadIdx.x;
    if (e < E) {
        int j = atomicAdd(&pos[dst[e]], 1);
        colw[j] = make_int2(src[e], __float_as_int(w[e]));
    }
}

// ---------------- Layer 1 (DIN=1, rank-1) fused: s=A_hat@x; x1=relu(s*W11 + x*W21 + b1); h2=x1@W1_2 (bf16)
__global__ void l1_fused_kernel(const float* __restrict__ x,
                                const int* __restrict__ row_start, const int2* __restrict__ colw,
                                const float* __restrict__ W11, const float* __restrict__ W21,
                                const float* __restrict__ b1, const float* __restrict__ W12,
                                float* __restrict__ x1, __hip_bfloat16* __restrict__ h2, int N) {
    __shared__ float w1s[CH][CH];
    __shared__ float xs[8][CH];
    int tid = threadIdx.x;  // 256
    for (int t = tid; t < CH * CH; t += 256) w1s[t >> 5][t & 31] = W12[t];
    int ln = tid >> 5, c = tid & 31;
    int node = blockIdx.x * 8 + ln;
    float s = 0.f, xv = 0.f;
    if (node < N) {
        xv = x[node];
        int lo = row_start[node], hi = row_start[node + 1];
        for (int j = lo + c; j < hi; j += 32) {
            int2 cw = colw[j];
            s += __int_as_float(cw.y) * x[cw.x];
        }
    }
    for (int m = 1; m < 32; m <<= 1) s += __shfl_xor(s, m);  // within 32-lane half
    float x1v = 0.f;
    if (node < N) {
        x1v = fmaxf(fmaf(s, W11[c], fmaf(xv, W21[c], b1[c])), 0.f);
        x1[node * CH + c] = x1v;
    }
    xs[ln][c] = x1v;
    __syncthreads();
    if (node < N) {
        float a = 0.f;
#pragma unroll
        for (int k = 0; k < CH; k++) a = fmaf(xs[ln][k], w1s[k][c], a);
        h2[node * CH + c] = __float2bfloat16(a);
    }
}

// h(bf16) = xin @ W1
__global__ void gemm_h_kernel(const float* __restrict__ xin, const float* __restrict__ W1,
                              __hip_bfloat16* __restrict__ h, int N) {
    __shared__ float w1s[CH][CH];
    __shared__ float xs[8][CH];
    int tid = threadIdx.x;
    for (int t = tid; t < CH * CH; t += 256) w1s[t >> 5][t & 31] = W1[t];
    int ln = tid >> 5, c = tid & 31;
    int node = blockIdx.x * 8 + ln;
    float xv = (node < N) ? xin[node * CH + c] : 0.f;
    xs[ln][c] = xv;
    __syncthreads();
    if (node < N) {
        float a = 0.f;
#pragma unroll
        for (int k = 0; k < CH; k++) a = fmaf(xs[ln][k], w1s[k][c], a);
        h[node * CH + c] = __float2bfloat16(a);
    }
}

// xio[i] = relu( sum_j w*h[col] + xio[i]@W2 + b )   (in-place; gather-reduce, no atomics)
__global__ void gather_kernel(float* __restrict__ xio, const __hip_bfloat16* __restrict__ h,
                              const int* __restrict__ row_start, const int2* __restrict__ colw,
                              const float* __restrict__ W2, const float* __restrict__ b, int N) {
    __shared__ float w2s[CH][CH];
    __shared__ float xs[8][CH];
    int tid = threadIdx.x;
    for (int t = tid; t < CH * CH; t += 256) w2s[t >> 5][t & 31] = W2[t];
    int ln = tid >> 5, c = tid & 31;
    int node = blockIdx.x * 8 + ln;
    float xv = (node < N) ? xio[node * CH + c] : 0.f;
    xs[ln][c] = xv;
    __syncthreads();
    if (node >= N) return;
    float acc = b[c];
#pragma unroll
    for (int k = 0; k < CH; k++) acc = fmaf(xs[ln][k], w2s[k][c], acc);
    int lo = row_start[node], hi = row_start[node + 1];
    int j = lo;
    for (; j + 2 <= hi; j += 2) {
        int2 cw0 = colw[j], cw1 = colw[j + 1];
        float h0 = __bfloat162float(h[(size_t)cw0.x * CH + c]);
        float h1 = __bfloat162float(h[(size_t)cw1.x * CH + c]);
        acc = fmaf(__int_as_float(cw0.y), h0, acc);
        acc = fmaf(__int_as_float(cw1.y), h1, acc);
    }
    if (j < hi) {
        int2 cw = colw[j];
        acc = fmaf(__int_as_float(cw.y), __bfloat162float(h[(size_t)cw.x * CH + c]), acc);
    }
    xio[node * CH + c] = fmaxf(acc, 0.f);
}

// seg is SORTED: one 64-thread block per graph; binary-search bounds; fused mean-pool + dense + sigmoid
__global__ void pool_head_kernel(const float* __restrict__ x3, const int* __restrict__ seg,
                                 const float* __restrict__ Wd, const float* __restrict__ bd,
                                 float* __restrict__ out, int N, int G) {
    int g = blockIdx.x;
    int tid = threadIdx.x;  // 64
    int lo = 0, hi = N;
    while (lo < hi) { int mid = (lo + hi) >> 1; if (seg[mid] < g) lo = mid + 1; else hi = mid; }
    int start = lo;
    hi = N;
    while (lo < hi) { int mid = (lo + hi) >> 1; if (seg[mid] < g + 1) lo = mid + 1; else hi = mid; }
    int end = lo;
    int half = tid >> 5, c = tid & 31;
    float s = 0.f;
    for (int n = start + half; n < end; n += 2) s += x3[n * CH + c];  // x3 already post-relu
    s += __shfl_xor(s, 32);
    float t = s * Wd[c];
    for (int m = 1; m < 32; m <<= 1) t += __shfl_xor(t, m);
    if (tid == 0) {
        float cnt = fmaxf((float)(end - start), 1.f);
        float logit = t / cnt + bd[0];
        out[g] = 1.f / (1.f + expf(-logit));
    }
}

extern "C" void kernel_launch(void* const* d_in, const int* in_sizes, int n_in,
                              void* d_out, int out_size, void* d_ws, size_t ws_size,
                              hipStream_t stream) {
    const float* x        = (const float*)d_in[0];
    const int*   edge_src = (const int*)d_in[1];
    const int*   edge_dst = (const int*)d_in[2];
    const float* edge_w   = (const float*)d_in[3];
    const int*   seg      = (const int*)d_in[4];
    const float* W1_1 = (const float*)d_in[5];
    const float* W2_1 = (const float*)d_in[6];
    const float* b1   = (const float*)d_in[7];
    const float* W1_2 = (const float*)d_in[8];
    const float* W2_2 = (const float*)d_in[9];
    const float* b2   = (const float*)d_in[10];
    const float* W1_3 = (const float*)d_in[11];
    const float* W2_3 = (const float*)d_in[12];
    const float* b3   = (const float*)d_in[13];
    const float* Wd   = (const float*)d_in[14];
    const float* bd   = (const float*)d_in[15];
    float* out = (float*)d_out;

    const int N = in_sizes[0];   // 262144
    const int E = in_sizes[1];   // 4194304
    const int G = out_size;      // 4096
    (void)ws_size; (void)n_in;

    const size_t NB = (size_t)N * CH;
    // ws layout: xbuf(f32 N*CH) | h16(bf16 N*CH) | row_start[N+4] | pos[N] | colw[E int2] | blockSums[1024]
    float*           xbuf      = (float*)d_ws;
    __hip_bfloat16*  h16       = (__hip_bfloat16*)(xbuf + NB);
    int*             row_start = (int*)(h16 + NB);
    int*             pos       = row_start + (N + 4);   // also serves as deg
    int2*            colw      = (int2*)(pos + N);
    int*             blockSums = (int*)(colw + E);

    const int BLK = 256;
    const int nb1024 = (N + 1023) / 1024;     // 256 scan blocks

    // ---- CSR build (dst-indexed) ----
    hipMemsetAsync(pos, 0, (size_t)N * sizeof(int), stream);
    hist_kernel<<<(E + BLK - 1) / BLK, BLK, 0, stream>>>(edge_dst, pos, E);
    scanA_kernel<<<nb1024, BLK, 0, stream>>>(pos, blockSums, N);
    scanB_kernel<<<1, 1024, 0, stream>>>(blockSums, nb1024);
    scanC_kernel<<<nb1024, BLK, 0, stream>>>(pos, blockSums, row_start, N);
    scatter_kernel<<<(E + BLK - 1) / BLK, BLK, 0, stream>>>(edge_src, edge_dst, edge_w, pos, colw, E);

    // ---- Layer 1 (fused: agg + out + h2 gemm) ----
    l1_fused_kernel<<<(N + 7) / 8, BLK, 0, stream>>>(x, row_start, colw,
                                                     W1_1, W2_1, b1, W1_2, xbuf, h16, N);
    // ---- Layer 2: x2 = relu(A@h2 + x1@W2_2 + b2), in place ----
    gather_kernel<<<(N + 7) / 8, BLK, 0, stream>>>(xbuf, h16, row_start, colw, W2_2, b2, N);
    // ---- Layer 3 ----
    gemm_h_kernel<<<(N + 7) / 8, BLK, 0, stream>>>(xbuf, W1_3, h16, N);
    gather_kernel<<<(N + 7) / 8, BLK, 0, stream>>>(xbuf, h16, row_start, colw, W2_3, b3, N);

    // ---- Fused pool + head (seg sorted -> binary search, no atomics) ----
    pool_head_kernel<<<G, 64, 0, stream>>>(xbuf, seg, Wd, bd, out, N, G);
}

// Round 4
// 569.484 us; speedup vs baseline: 2.3888x; 1.6235x over previous
//
#include <hip/hip_runtime.h>
#include <hip/hip_bf16.h>

#define CH 32
#define BSHIFT 10                 // 1024 nodes per bucket
#define BNODES (1 << BSHIFT)
#define MAXBUK 256
#define P3_CHUNK 8192

// ---------------- Bucketed CSR build ----------------

// Phase 1: global bucket histogram via LDS
__global__ void bucket_hist_kernel(const int* __restrict__ dst, int* __restrict__ bucketCount,
                                   int E, int nbuk) {
    __shared__ int h[MAXBUK];
    int tid = threadIdx.x;
    if (tid < nbuk) h[tid] = 0;
    __syncthreads();
    int stride = gridDim.x * blockDim.x;
    for (int e = blockIdx.x * blockDim.x + tid; e < E; e += stride)
        atomicAdd(&h[dst[e] >> BSHIFT], 1);
    __syncthreads();
    if (tid < nbuk && h[tid]) atomicAdd(&bucketCount[tid], h[tid]);
}

// Phase 2: exclusive scan of bucketCount (nbuk <= 256); init bucketTail; row_start[N] = E
__global__ void bucket_scan_kernel(const int* __restrict__ bucketCount, int* __restrict__ bucketStart,
                                   int* __restrict__ bucketTail, int* __restrict__ row_start,
                                   int nbuk, int N, int E) {
    __shared__ int l[MAXBUK];
    int tid = threadIdx.x;  // 256
    int v = (tid < nbuk) ? bucketCount[tid] : 0;
    l[tid] = v;
    __syncthreads();
    for (int off = 1; off < MAXBUK; off <<= 1) {
        int t = (tid >= off) ? l[tid - off] : 0;
        __syncthreads();
        l[tid] += t;
        __syncthreads();
    }
    int ex = l[tid] - v;
    if (tid < nbuk) { bucketStart[tid] = ex; bucketTail[tid] = ex; }
    if (tid == nbuk - 1) bucketStart[nbuk] = ex + v;
    if (tid == 0) row_start[N] = E;
}

// Phase 3: bin edges into bucket regions; packed rec = {src | dstLow<<18, bits(w)}
// (valid for N <= 2^18; harness N = 262144)
__global__ void bucket_scatter_kernel(const int* __restrict__ src, const int* __restrict__ dst,
                                      const float* __restrict__ w, int* __restrict__ bucketTail,
                                      int2* __restrict__ rec, int E, int nbuk) {
    __shared__ int cnt[MAXBUK], base[MAXBUK], offs[MAXBUK];
    int tid = threadIdx.x;  // 256
    int begin = blockIdx.x * P3_CHUNK;
    int end = min(begin + P3_CHUNK, E);
    if (tid < nbuk) cnt[tid] = 0;
    __syncthreads();
    for (int e = begin + tid; e < end; e += 256)
        atomicAdd(&cnt[dst[e] >> BSHIFT], 1);
    __syncthreads();
    if (tid < nbuk) {
        base[tid] = cnt[tid] ? atomicAdd(&bucketTail[tid], cnt[tid]) : 0;
        offs[tid] = 0;
    }
    __syncthreads();
    for (int e = begin + tid; e < end; e += 256) {
        int d = dst[e];
        int b = d >> BSHIFT;
        int p = base[b] + atomicAdd(&offs[b], 1);
        rec[p] = make_int2(src[e] | ((d & (BNODES - 1)) << 18), __float_as_int(w[e]));
    }
}

// Phase 4: per-bucket local CSR: LDS deg/scan -> row_start + compact colw (L2-resident scatter)
__global__ void local_csr_kernel(const int2* __restrict__ rec, const int* __restrict__ bucketStart,
                                 int* __restrict__ row_start, int2* __restrict__ colw, int N) {
    int b = blockIdx.x;
    int lo = bucketStart[b], hi = bucketStart[b + 1];
    int nodeBase = b << BSHIFT;
    int nNodes = min(BNODES, N - nodeBase);
    __shared__ int deg[BNODES];
    __shared__ int rs[BNODES];
    __shared__ int l[256];
    int tid = threadIdx.x;  // 256
    for (int i = tid; i < BNODES; i += 256) deg[i] = 0;
    __syncthreads();
    for (int j = lo + tid; j < hi; j += 256)
        atomicAdd(&deg[rec[j].x >> 18], 1);
    __syncthreads();
    // exclusive scan of deg[0..1023]: 4 per thread
    int i0 = tid * 4;
    int v0 = deg[i0], v1 = deg[i0 + 1], v2 = deg[i0 + 2], v3 = deg[i0 + 3];
    int tsum = v0 + v1 + v2 + v3;
    l[tid] = tsum;
    __syncthreads();
    for (int off = 1; off < 256; off <<= 1) {
        int t = (tid >= off) ? l[tid - off] : 0;
        __syncthreads();
        l[tid] += t;
        __syncthreads();
    }
    int ex = l[tid] - tsum;
    rs[i0] = ex; rs[i0 + 1] = ex + v0; rs[i0 + 2] = ex + v0 + v1; rs[i0 + 3] = ex + v0 + v1 + v2;
    __syncthreads();
    for (int i = tid; i < nNodes; i += 256) row_start[nodeBase + i] = lo + rs[i];
    // reuse deg as per-node alloc counters
    for (int i = tid; i < BNODES; i += 256) deg[i] = 0;
    __syncthreads();
    for (int j = lo + tid; j < hi; j += 256) {
        int2 r = rec[j];
        int dl = r.x >> 18;
        int p = lo + rs[dl] + atomicAdd(&deg[dl], 1);
        colw[p] = make_int2(r.x & 0x3FFFF, r.y);
    }
}

// ---------------- Layer 1 (DIN=1, rank-1) fused: s=A_hat@x; x1=relu(s*W11 + x*W21 + b1); h2=x1@W1_2 (bf16)
__global__ void l1_fused_kernel(const float* __restrict__ x,
                                const int* __restrict__ row_start, const int2* __restrict__ colw,
                                const float* __restrict__ W11, const float* __restrict__ W21,
                                const float* __restrict__ b1, const float* __restrict__ W12,
                                float* __restrict__ x1, __hip_bfloat16* __restrict__ h2, int N) {
    __shared__ float w1s[CH][CH];
    __shared__ float xs[8][CH];
    int tid = threadIdx.x;  // 256
    for (int t = tid; t < CH * CH; t += 256) w1s[t >> 5][t & 31] = W12[t];
    int ln = tid >> 5, c = tid & 31;
    int node = blockIdx.x * 8 + ln;
    float s = 0.f, xv = 0.f;
    if (node < N) {
        xv = x[node];
        int lo = row_start[node], hi = row_start[node + 1];
        for (int j = lo + c; j < hi; j += 32) {
            int2 cw = colw[j];
            s += __int_as_float(cw.y) * x[cw.x];
        }
    }
    for (int m = 1; m < 32; m <<= 1) s += __shfl_xor(s, m);  // within 32-lane half
    float x1v = 0.f;
    if (node < N) {
        x1v = fmaxf(fmaf(s, W11[c], fmaf(xv, W21[c], b1[c])), 0.f);
        x1[node * CH + c] = x1v;
    }
    xs[ln][c] = x1v;
    __syncthreads();
    if (node < N) {
        float a = 0.f;
#pragma unroll
        for (int k = 0; k < CH; k++) a = fmaf(xs[ln][k], w1s[k][c], a);
        h2[node * CH + c] = __float2bfloat16(a);
    }
}

// h(bf16) = xin @ W1
__global__ void gemm_h_kernel(const float* __restrict__ xin, const float* __restrict__ W1,
                              __hip_bfloat16* __restrict__ h, int N) {
    __shared__ float w1s[CH][CH];
    __shared__ float xs[8][CH];
    int tid = threadIdx.x;
    for (int t = tid; t < CH * CH; t += 256) w1s[t >> 5][t & 31] = W1[t];
    int ln = tid >> 5, c = tid & 31;
    int node = blockIdx.x * 8 + ln;
    float xv = (node < N) ? xin[node * CH + c] : 0.f;
    xs[ln][c] = xv;
    __syncthreads();
    if (node < N) {
        float a = 0.f;
#pragma unroll
        for (int k = 0; k < CH; k++) a = fmaf(xs[ln][k], w1s[k][c], a);
        h[node * CH + c] = __float2bfloat16(a);
    }
}

// xio[i] = relu( sum_j w*h[col] + xio[i]@W2 + b )   (in-place; gather-reduce, no atomics)
__global__ void gather_kernel(float* __restrict__ xio, const __hip_bfloat16* __restrict__ h,
                              const int* __restrict__ row_start, const int2* __restrict__ colw,
                              const float* __restrict__ W2, const float* __restrict__ b, int N) {
    __shared__ float w2s[CH][CH];
    __shared__ float xs[8][CH];
    int tid = threadIdx.x;
    for (int t = tid; t < CH * CH; t += 256) w2s[t >> 5][t & 31] = W2[t];
    int ln = tid >> 5, c = tid & 31;
    int node = blockIdx.x * 8 + ln;
    float xv = (node < N) ? xio[node * CH + c] : 0.f;
    xs[ln][c] = xv;
    __syncthreads();
    if (node >= N) return;
    float acc = b[c];
#pragma unroll
    for (int k = 0; k < CH; k++) acc = fmaf(xs[ln][k], w2s[k][c], acc);
    int lo = row_start[node], hi = row_start[node + 1];
    int j = lo;
    for (; j + 2 <= hi; j += 2) {
        int2 cw0 = colw[j], cw1 = colw[j + 1];
        float h0 = __bfloat162float(h[(size_t)cw0.x * CH + c]);
        float h1 = __bfloat162float(h[(size_t)cw1.x * CH + c]);
        acc = fmaf(__int_as_float(cw0.y), h0, acc);
        acc = fmaf(__int_as_float(cw1.y), h1, acc);
    }
    if (j < hi) {
        int2 cw = colw[j];
        acc = fmaf(__int_as_float(cw.y), __bfloat162float(h[(size_t)cw.x * CH + c]), acc);
    }
    xio[node * CH + c] = fmaxf(acc, 0.f);
}

// seg is SORTED: one 64-thread block per graph; binary-search bounds; fused mean-pool + dense + sigmoid
__global__ void pool_head_kernel(const float* __restrict__ x3, const int* __restrict__ seg,
                                 const float* __restrict__ Wd, const float* __restrict__ bd,
                                 float* __restrict__ out, int N, int G) {
    int g = blockIdx.x;
    int tid = threadIdx.x;  // 64
    int lo = 0, hi = N;
    while (lo < hi) { int mid = (lo + hi) >> 1; if (seg[mid] < g) lo = mid + 1; else hi = mid; }
    int start = lo;
    hi = N;
    while (lo < hi) { int mid = (lo + hi) >> 1; if (seg[mid] < g + 1) lo = mid + 1; else hi = mid; }
    int end = lo;
    int half = tid >> 5, c = tid & 31;
    float s = 0.f;
    for (int n = start + half; n < end; n += 2) s += x3[n * CH + c];  // x3 already post-relu
    s += __shfl_xor(s, 32);
    float t = s * Wd[c];
    for (int m = 1; m < 32; m <<= 1) t += __shfl_xor(t, m);
    if (tid == 0) {
        float cnt = fmaxf((float)(end - start), 1.f);
        float logit = t / cnt + bd[0];
        out[g] = 1.f / (1.f + expf(-logit));
    }
}

extern "C" void kernel_launch(void* const* d_in, const int* in_sizes, int n_in,
                              void* d_out, int out_size, void* d_ws, size_t ws_size,
                              hipStream_t stream) {
    const float* x        = (const float*)d_in[0];
    const int*   edge_src = (const int*)d_in[1];
    const int*   edge_dst = (const int*)d_in[2];
    const float* edge_w   = (const float*)d_in[3];
    const int*   seg      = (const int*)d_in[4];
    const float* W1_1 = (const float*)d_in[5];
    const float* W2_1 = (const float*)d_in[6];
    const float* b1   = (const float*)d_in[7];
    const float* W1_2 = (const float*)d_in[8];
    const float* W2_2 = (const float*)d_in[9];
    const float* b2   = (const float*)d_in[10];
    const float* W1_3 = (const float*)d_in[11];
    const float* W2_3 = (const float*)d_in[12];
    const float* b3   = (const float*)d_in[13];
    const float* Wd   = (const float*)d_in[14];
    const float* bd   = (const float*)d_in[15];
    float* out = (float*)d_out;

    const int N = in_sizes[0];   // 262144
    const int E = in_sizes[1];   // 4194304
    const int G = out_size;      // 4096
    (void)ws_size; (void)n_in;

    const int nbuk = (N + BNODES - 1) >> BSHIFT;   // 256

    const size_t NB = (size_t)N * CH;
    // ws layout: xbuf(f32 N*CH, aliased by rec during CSR build) | h16(bf16 N*CH) |
    //            row_start[N+8] | colw[E int2] | bucketCount/Start/Tail
    float*           xbuf      = (float*)d_ws;
    int2*            rec       = (int2*)d_ws;              // alias: dead before l1_fused
    __hip_bfloat16*  h16       = (__hip_bfloat16*)(xbuf + NB);
    int*             row_start = (int*)(h16 + NB);
    int2*            colw      = (int2*)(row_start + (N + 8));
    int*             bucketCount = (int*)(colw + E);
    int*             bucketStart = bucketCount + MAXBUK;
    int*             bucketTail  = bucketStart + MAXBUK + 4;

    const int BLK = 256;

    // ---- CSR build via two-level bucket sort ----
    hipMemsetAsync(bucketCount, 0, MAXBUK * sizeof(int), stream);
    bucket_hist_kernel<<<512, BLK, 0, stream>>>(edge_dst, bucketCount, E, nbuk);
    bucket_scan_kernel<<<1, BLK, 0, stream>>>(bucketCount, bucketStart, bucketTail, row_start, nbuk, N, E);
    bucket_scatter_kernel<<<(E + P3_CHUNK - 1) / P3_CHUNK, BLK, 0, stream>>>(
        edge_src, edge_dst, edge_w, bucketTail, rec, E, nbuk);
    local_csr_kernel<<<nbuk, BLK, 0, stream>>>(rec, bucketStart, row_start, colw, N);

    // ---- Layer 1 (fused: agg + out + h2 gemm) ----
    l1_fused_kernel<<<(N + 7) / 8, BLK, 0, stream>>>(x, row_start, colw,
                                                     W1_1, W2_1, b1, W1_2, xbuf, h16, N);
    // ---- Layer 2: x2 = relu(A@h2 + x1@W2_2 + b2), in place ----
    gather_kernel<<<(N + 7) / 8, BLK, 0, stream>>>(xbuf, h16, row_start, colw, W2_2, b2, N);
    // ---- Layer 3 ----
    gemm_h_kernel<<<(N + 7) / 8, BLK, 0, stream>>>(xbuf, W1_3, h16, N);
    gather_kernel<<<(N + 7) / 8, BLK, 0, stream>>>(xbuf, h16, row_start, colw, W2_3, b3, N);

    // ---- Fused pool + head (seg sorted -> binary search, no atomics) ----
    pool_head_kernel<<<G, 64, 0, stream>>>(xbuf, seg, Wd, bd, out, N, G);
}

// Round 5
// 447.477 us; speedup vs baseline: 3.0402x; 1.2727x over previous
//
#include <hip/hip_runtime.h>
#include <hip/hip_bf16.h>

#define CH 32
#define BSHIFT 10                 // 1024 nodes per bucket
#define BNODES (1 << BSHIFT)
#define MAXBUK 256
#define P3_CHUNK 8192
#define NT 32                     // nodes per gather block
#define CAP 2048                  // staged colw entries per gather block

__device__ __forceinline__ float bf_lo(unsigned int p) { return __int_as_float(p << 16); }
__device__ __forceinline__ float bf_hi(unsigned int p) { return __int_as_float(p & 0xffff0000u); }

// ---------------- Bucketed CSR build ----------------

__global__ void bucket_hist_kernel(const int* __restrict__ dst, int* __restrict__ bucketCount,
                                   int E, int nbuk) {
    __shared__ int h[MAXBUK];
    int tid = threadIdx.x;
    if (tid < nbuk) h[tid] = 0;
    __syncthreads();
    int stride = gridDim.x * blockDim.x;
    for (int e = blockIdx.x * blockDim.x + tid; e < E; e += stride)
        atomicAdd(&h[dst[e] >> BSHIFT], 1);
    __syncthreads();
    if (tid < nbuk && h[tid]) atomicAdd(&bucketCount[tid], h[tid]);
}

__global__ void bucket_scan_kernel(const int* __restrict__ bucketCount, int* __restrict__ bucketStart,
                                   int* __restrict__ bucketTail, int* __restrict__ row_start,
                                   int nbuk, int N, int E) {
    __shared__ int l[MAXBUK];
    int tid = threadIdx.x;  // 256
    int v = (tid < nbuk) ? bucketCount[tid] : 0;
    l[tid] = v;
    __syncthreads();
    for (int off = 1; off < MAXBUK; off <<= 1) {
        int t = (tid >= off) ? l[tid - off] : 0;
        __syncthreads();
        l[tid] += t;
        __syncthreads();
    }
    int ex = l[tid] - v;
    if (tid < nbuk) { bucketStart[tid] = ex; bucketTail[tid] = ex; }
    if (tid == nbuk - 1) bucketStart[nbuk] = ex + v;
    if (tid == 0) row_start[N] = E;
}

// rec = {src | dstLow<<18, bits(w)}  (valid for N <= 2^18)
__global__ void bucket_scatter_kernel(const int* __restrict__ src, const int* __restrict__ dst,
                                      const float* __restrict__ w, int* __restrict__ bucketTail,
                                      int2* __restrict__ rec, int E, int nbuk) {
    __shared__ int cnt[MAXBUK], base[MAXBUK], offs[MAXBUK];
    int tid = threadIdx.x;  // 256
    int begin = blockIdx.x * P3_CHUNK;
    int end = min(begin + P3_CHUNK, E);
    if (tid < nbuk) cnt[tid] = 0;
    __syncthreads();
    for (int e = begin + tid; e < end; e += 256)
        atomicAdd(&cnt[dst[e] >> BSHIFT], 1);
    __syncthreads();
    if (tid < nbuk) {
        base[tid] = cnt[tid] ? atomicAdd(&bucketTail[tid], cnt[tid]) : 0;
        offs[tid] = 0;
    }
    __syncthreads();
    for (int e = begin + tid; e < end; e += 256) {
        int d = dst[e];
        int b = d >> BSHIFT;
        int p = base[b] + atomicAdd(&offs[b], 1);
        rec[p] = make_int2(src[e] | ((d & (BNODES - 1)) << 18), __float_as_int(w[e]));
    }
}

__global__ void local_csr_kernel(const int2* __restrict__ rec, const int* __restrict__ bucketStart,
                                 int* __restrict__ row_start, int2* __restrict__ colw, int N) {
    int b = blockIdx.x;
    int lo = bucketStart[b], hi = bucketStart[b + 1];
    int nodeBase = b << BSHIFT;
    int nNodes = min(BNODES, N - nodeBase);
    __shared__ int deg[BNODES];
    __shared__ int rs[BNODES];
    __shared__ int l[256];
    int tid = threadIdx.x;  // 256
    for (int i = tid; i < BNODES; i += 256) deg[i] = 0;
    __syncthreads();
    for (int j = lo + tid; j < hi; j += 256)
        atomicAdd(&deg[rec[j].x >> 18], 1);
    __syncthreads();
    int i0 = tid * 4;
    int v0 = deg[i0], v1 = deg[i0 + 1], v2 = deg[i0 + 2], v3 = deg[i0 + 3];
    int tsum = v0 + v1 + v2 + v3;
    l[tid] = tsum;
    __syncthreads();
    for (int off = 1; off < 256; off <<= 1) {
        int t = (tid >= off) ? l[tid - off] : 0;
        __syncthreads();
        l[tid] += t;
        __syncthreads();
    }
    int ex = l[tid] - tsum;
    rs[i0] = ex; rs[i0 + 1] = ex + v0; rs[i0 + 2] = ex + v0 + v1; rs[i0 + 3] = ex + v0 + v1 + v2;
    __syncthreads();
    for (int i = tid; i < nNodes; i += 256) row_start[nodeBase + i] = lo + rs[i];
    for (int i = tid; i < BNODES; i += 256) deg[i] = 0;
    __syncthreads();
    for (int j = lo + tid; j < hi; j += 256) {
        int2 r = rec[j];
        int dl = r.x >> 18;
        int p = lo + rs[dl] + atomicAdd(&deg[dl], 1);
        colw[p] = make_int2(r.x & 0x3FFFF, r.y);
    }
}

// ---------------- Layer 1 fused ----------------
__global__ void l1_fused_kernel(const float* __restrict__ x,
                                const int* __restrict__ row_start, const int2* __restrict__ colw,
                                const float* __restrict__ W11, const float* __restrict__ W21,
                                const float* __restrict__ b1, const float* __restrict__ W12,
                                float* __restrict__ x1, __hip_bfloat16* __restrict__ h2, int N) {
    __shared__ float w1s[CH][CH];
    __shared__ float xs[8][CH + 1];
    int tid = threadIdx.x;  // 256
    for (int t = tid; t < CH * CH; t += 256) w1s[t >> 5][t & 31] = W12[t];
    int ln = tid >> 5, c = tid & 31;
    int node = blockIdx.x * 8 + ln;
    float s = 0.f, xv = 0.f;
    if (node < N) {
        xv = x[node];
        int lo = row_start[node], hi = row_start[node + 1];
        for (int j = lo + c; j < hi; j += 32) {
            int2 cw = colw[j];
            s += __int_as_float(cw.y) * x[cw.x];
        }
    }
    for (int m = 1; m < 32; m <<= 1) s += __shfl_xor(s, m);
    float x1v = 0.f;
    if (node < N) {
        x1v = fmaxf(fmaf(s, W11[c], fmaf(xv, W21[c], b1[c])), 0.f);
        x1[node * CH + c] = x1v;
    }
    xs[ln][c] = x1v;
    __syncthreads();
    if (node < N) {
        float a = 0.f;
#pragma unroll
        for (int k = 0; k < CH; k++) a = fmaf(xs[ln][k], w1s[k][c], a);
        h2[node * CH + c] = __float2bfloat16(a);
    }
}

// h(bf16) = xin @ W1
__global__ void gemm_h_kernel(const float* __restrict__ xin, const float* __restrict__ W1,
                              __hip_bfloat16* __restrict__ h, int N) {
    __shared__ float w1s[CH][CH];
    __shared__ float xs[8][CH + 1];
    int tid = threadIdx.x;
    for (int t = tid; t < CH * CH; t += 256) w1s[t >> 5][t & 31] = W1[t];
    int ln = tid >> 5, c = tid & 31;
    int node = blockIdx.x * 8 + ln;
    float xv = (node < N) ? xin[node * CH + c] : 0.f;
    xs[ln][c] = xv;
    __syncthreads();
    if (node < N) {
        float a = 0.f;
#pragma unroll
        for (int k = 0; k < CH; k++) a = fmaf(xs[ln][k], w1s[k][c], a);
        h[node * CH + c] = __float2bfloat16(a);
    }
}

// ---------------- Gather v2: LDS-staged colw, ushort2 h loads, 4-deep ILP ----------------
// xio[n] = relu( sum_j w*h[col] + xio[n]@W2 + b ), in place. h = bf16 bit pattern (ushort).
__global__ void gather_kernel(float* __restrict__ xio, const unsigned short* __restrict__ h,
                              const int* __restrict__ row_start, const int2* __restrict__ colw,
                              const float* __restrict__ W2, const float* __restrict__ b, int N) {
    __shared__ float w2s[CH][CH];
    __shared__ float xs[NT][CH + 1];
    __shared__ int2 cws[CAP];
    int tid = threadIdx.x;  // 256
    int nodeBase = blockIdx.x * NT;

    for (int t = tid; t < CH * CH; t += 256) w2s[t >> 5][t & 31] = W2[t];
    {
        int n = tid >> 5, c = tid & 31;
        for (int p = 0; p < NT / 8; p++) {
            int node = nodeBase + p * 8 + n;
            xs[p * 8 + n][c] = (node < N) ? xio[(size_t)node * CH + c] : 0.f;
        }
    }
    int tileEndNode = min(nodeBase + NT, N);
    int lo = row_start[min(nodeBase, N)];
    int hi = row_start[tileEndNode];
    int cnt = min(hi - lo, CAP);
    for (int t = tid; t < cnt; t += 256) cws[t] = colw[lo + t];
    __syncthreads();

    int grp = tid >> 4, l16 = tid & 15;   // 16 groups of 16 lanes
    int c0 = l16 * 2;
#pragma unroll
    for (int rep = 0; rep < NT / 16; rep++) {
        int nloc = rep * 16 + grp;
        int node = nodeBase + nloc;
        if (node >= N) continue;
        int ls = row_start[node], le = row_start[node + 1];
        float a0 = b[c0], a1 = b[c0 + 1];
#pragma unroll
        for (int k = 0; k < CH; k++) {
            float xk = xs[nloc][k];
            float2 wk = *reinterpret_cast<const float2*>(&w2s[k][c0]);
            a0 = fmaf(xk, wk.x, a0);
            a1 = fmaf(xk, wk.y, a1);
        }
        if (le - lo <= cnt) {
            int j = ls;
            for (; j + 4 <= le; j += 4) {
                int2 e0 = cws[j - lo], e1 = cws[j + 1 - lo], e2 = cws[j + 2 - lo], e3 = cws[j + 3 - lo];
                unsigned int p0 = *reinterpret_cast<const unsigned int*>(h + (size_t)e0.x * CH + c0);
                unsigned int p1 = *reinterpret_cast<const unsigned int*>(h + (size_t)e1.x * CH + c0);
                unsigned int p2 = *reinterpret_cast<const unsigned int*>(h + (size_t)e2.x * CH + c0);
                unsigned int p3 = *reinterpret_cast<const unsigned int*>(h + (size_t)e3.x * CH + c0);
                float w0 = __int_as_float(e0.y), w1 = __int_as_float(e1.y);
                float w2 = __int_as_float(e2.y), w3 = __int_as_float(e3.y);
                a0 = fmaf(w0, bf_lo(p0), a0); a1 = fmaf(w0, bf_hi(p0), a1);
                a0 = fmaf(w1, bf_lo(p1), a0); a1 = fmaf(w1, bf_hi(p1), a1);
                a0 = fmaf(w2, bf_lo(p2), a0); a1 = fmaf(w2, bf_hi(p2), a1);
                a0 = fmaf(w3, bf_lo(p3), a0); a1 = fmaf(w3, bf_hi(p3), a1);
            }
            for (; j < le; j++) {
                int2 e = cws[j - lo];
                unsigned int p = *reinterpret_cast<const unsigned int*>(h + (size_t)e.x * CH + c0);
                float wj = __int_as_float(e.y);
                a0 = fmaf(wj, bf_lo(p), a0); a1 = fmaf(wj, bf_hi(p), a1);
            }
        } else {
            for (int j = ls; j < le; j++) {
                int2 e = colw[j];
                unsigned int p = *reinterpret_cast<const unsigned int*>(h + (size_t)e.x * CH + c0);
                float wj = __int_as_float(e.y);
                a0 = fmaf(wj, bf_lo(p), a0); a1 = fmaf(wj, bf_hi(p), a1);
            }
        }
        float2 o = make_float2(fmaxf(a0, 0.f), fmaxf(a1, 0.f));
        *reinterpret_cast<float2*>(&xio[(size_t)node * CH + c0]) = o;
    }
}

// seg SORTED: one 64-thread block per graph; fused mean-pool + dense + sigmoid
__global__ void pool_head_kernel(const float* __restrict__ x3, const int* __restrict__ seg,
                                 const float* __restrict__ Wd, const float* __restrict__ bd,
                                 float* __restrict__ out, int N, int G) {
    int g = blockIdx.x;
    int tid = threadIdx.x;  // 64
    int lo = 0, hi = N;
    while (lo < hi) { int mid = (lo + hi) >> 1; if (seg[mid] < g) lo = mid + 1; else hi = mid; }
    int start = lo;
    hi = N;
    while (lo < hi) { int mid = (lo + hi) >> 1; if (seg[mid] < g + 1) lo = mid + 1; else hi = mid; }
    int end = lo;
    int half = tid >> 5, c = tid & 31;
    float s = 0.f;
    for (int n = start + half; n < end; n += 2) s += x3[(size_t)n * CH + c];
    s += __shfl_xor(s, 32);
    float t = s * Wd[c];
    for (int m = 1; m < 32; m <<= 1) t += __shfl_xor(t, m);
    if (tid == 0) {
        float cnt = fmaxf((float)(end - start), 1.f);
        float logit = t / cnt + bd[0];
        out[g] = 1.f / (1.f + expf(-logit));
    }
}

extern "C" void kernel_launch(void* const* d_in, const int* in_sizes, int n_in,
                              void* d_out, int out_size, void* d_ws, size_t ws_size,
                              hipStream_t stream) {
    const float* x        = (const float*)d_in[0];
    const int*   edge_src = (const int*)d_in[1];
    const int*   edge_dst = (const int*)d_in[2];
    const float* edge_w   = (const float*)d_in[3];
    const int*   seg      = (const int*)d_in[4];
    const float* W1_1 = (const float*)d_in[5];
    const float* W2_1 = (const float*)d_in[6];
    const float* b1   = (const float*)d_in[7];
    const float* W1_2 = (const float*)d_in[8];
    const float* W2_2 = (const float*)d_in[9];
    const float* b2   = (const float*)d_in[10];
    const float* W1_3 = (const float*)d_in[11];
    const float* W2_3 = (const float*)d_in[12];
    const float* b3   = (const float*)d_in[13];
    const float* Wd   = (const float*)d_in[14];
    const float* bd   = (const float*)d_in[15];
    float* out = (float*)d_out;

    const int N = in_sizes[0];   // 262144
    const int E = in_sizes[1];   // 4194304
    const int G = out_size;      // 4096
    (void)ws_size; (void)n_in;

    const int nbuk = (N + BNODES - 1) >> BSHIFT;   // 256

    const size_t NB = (size_t)N * CH;
    float*           xbuf      = (float*)d_ws;
    int2*            rec       = (int2*)d_ws;              // alias: dead before l1_fused
    __hip_bfloat16*  h16       = (__hip_bfloat16*)(xbuf + NB);
    int*             row_start = (int*)(h16 + NB);
    int2*            colw      = (int2*)(row_start + (N + 8));
    int*             bucketCount = (int*)(colw + E);
    int*             bucketStart = bucketCount + MAXBUK;
    int*             bucketTail  = bucketStart + MAXBUK + 4;

    const int BLK = 256;

    // ---- CSR build via two-level bucket sort ----
    hipMemsetAsync(bucketCount, 0, MAXBUK * sizeof(int), stream);
    bucket_hist_kernel<<<512, BLK, 0, stream>>>(edge_dst, bucketCount, E, nbuk);
    bucket_scan_kernel<<<1, BLK, 0, stream>>>(bucketCount, bucketStart, bucketTail, row_start, nbuk, N, E);
    bucket_scatter_kernel<<<(E + P3_CHUNK - 1) / P3_CHUNK, BLK, 0, stream>>>(
        edge_src, edge_dst, edge_w, bucketTail, rec, E, nbuk);
    local_csr_kernel<<<nbuk, BLK, 0, stream>>>(rec, bucketStart, row_start, colw, N);

    // ---- Layer 1 (fused: agg + out + h2 gemm) ----
    l1_fused_kernel<<<(N + 7) / 8, BLK, 0, stream>>>(x, row_start, colw,
                                                     W1_1, W2_1, b1, W1_2, xbuf, h16, N);
    // ---- Layer 2 ----
    gather_kernel<<<(N + NT - 1) / NT, BLK, 0, stream>>>(xbuf, (const unsigned short*)h16,
                                                         row_start, colw, W2_2, b2, N);
    // ---- Layer 3 ----
    gemm_h_kernel<<<(N + 7) / 8, BLK, 0, stream>>>(xbuf, W1_3, h16, N);
    gather_kernel<<<(N + NT - 1) / NT, BLK, 0, stream>>>(xbuf, (const unsigned short*)h16,
                                                         row_start, colw, W2_3, b3, N);

    // ---- Fused pool + head ----
    pool_head_kernel<<<G, 64, 0, stream>>>(xbuf, seg, Wd, bd, out, N, G);
}

// Round 7
// 411.748 us; speedup vs baseline: 3.3040x; 1.0868x over previous
//
#include <hip/hip_runtime.h>
#include <hip/hip_bf16.h>
#include <hip/hip_fp8.h>

#define CH 32
#define BSHIFT 10                 // 1024 nodes per bucket
#define BNODES (1 << BSHIFT)
#define MAXBUK 256
#define P3_CHUNK 8192
#define NT 32                     // nodes per gather block
#define CAP 1024                  // staged colw entries per gather block

__device__ __forceinline__ float fp8_to_f32(unsigned int b) {
    __hip_fp8_e4m3 v; v.__x = (__hip_fp8_storage_t)b; return (float)v;
}
__device__ __forceinline__ unsigned char f32_to_fp8(float f) {
    return (unsigned char)__hip_fp8_e4m3(f).__x;
}

// ---------------- Bucketed CSR build ----------------

__global__ void bucket_hist_kernel(const int* __restrict__ dst, int* __restrict__ bucketCount,
                                   int E, int nbuk) {
    __shared__ int h[MAXBUK];
    int tid = threadIdx.x;
    if (tid < nbuk) h[tid] = 0;
    __syncthreads();
    int stride = gridDim.x * blockDim.x;
    for (int e = blockIdx.x * blockDim.x + tid; e < E; e += stride)
        atomicAdd(&h[dst[e] >> BSHIFT], 1);
    __syncthreads();
    if (tid < nbuk && h[tid]) atomicAdd(&bucketCount[tid], h[tid]);
}

__global__ void bucket_scan_kernel(const int* __restrict__ bucketCount, int* __restrict__ bucketStart,
                                   int* __restrict__ bucketTail, int* __restrict__ row_start,
                                   int nbuk, int N, int E) {
    __shared__ int l[MAXBUK];
    int tid = threadIdx.x;  // 256
    int v = (tid < nbuk) ? bucketCount[tid] : 0;
    l[tid] = v;
    __syncthreads();
    for (int off = 1; off < MAXBUK; off <<= 1) {
        int t = (tid >= off) ? l[tid - off] : 0;
        __syncthreads();
        l[tid] += t;
        __syncthreads();
    }
    int ex = l[tid] - v;
    if (tid < nbuk) { bucketStart[tid] = ex; bucketTail[tid] = ex; }
    if (tid == nbuk - 1) bucketStart[nbuk] = ex + v;
    if (tid == 0) row_start[N] = E;
}

// rec = {src | dstLow<<18, bits(w)}  (valid for N <= 2^18)
__global__ void bucket_scatter_kernel(const int* __restrict__ src, const int* __restrict__ dst,
                                      const float* __restrict__ w, int* __restrict__ bucketTail,
                                      int2* __restrict__ rec, int E, int nbuk) {
    __shared__ int cnt[MAXBUK], base[MAXBUK], offs[MAXBUK];
    int tid = threadIdx.x;  // 256
    int begin = blockIdx.x * P3_CHUNK;
    int end = min(begin + P3_CHUNK, E);
    if (tid < nbuk) cnt[tid] = 0;
    __syncthreads();
    for (int e = begin + tid; e < end; e += 256)
        atomicAdd(&cnt[dst[e] >> BSHIFT], 1);
    __syncthreads();
    if (tid < nbuk) {
        base[tid] = cnt[tid] ? atomicAdd(&bucketTail[tid], cnt[tid]) : 0;
        offs[tid] = 0;
    }
    __syncthreads();
    for (int e = begin + tid; e < end; e += 256) {
        int d = dst[e];
        int b = d >> BSHIFT;
        int p = base[b] + atomicAdd(&offs[b], 1);
        rec[p] = make_int2(src[e] | ((d & (BNODES - 1)) << 18), __float_as_int(w[e]));
    }
}

__global__ void local_csr_kernel(const int2* __restrict__ rec, const int* __restrict__ bucketStart,
                                 int* __restrict__ row_start, int2* __restrict__ colw, int N) {
    int b = blockIdx.x;
    int lo = bucketStart[b], hi = bucketStart[b + 1];
    int nodeBase = b << BSHIFT;
    int nNodes = min(BNODES, N - nodeBase);
    __shared__ int deg[BNODES];
    __shared__ int rs[BNODES];
    __shared__ int l[256];
    int tid = threadIdx.x;  // 256
    for (int i = tid; i < BNODES; i += 256) deg[i] = 0;
    __syncthreads();
    for (int j = lo + tid; j < hi; j += 256)
        atomicAdd(&deg[rec[j].x >> 18], 1);
    __syncthreads();
    int i0 = tid * 4;
    int v0 = deg[i0], v1 = deg[i0 + 1], v2 = deg[i0 + 2], v3 = deg[i0 + 3];
    int tsum = v0 + v1 + v2 + v3;
    l[tid] = tsum;
    __syncthreads();
    for (int off = 1; off < 256; off <<= 1) {
        int t = (tid >= off) ? l[tid - off] : 0;
        __syncthreads();
        l[tid] += t;
        __syncthreads();
    }
    int ex = l[tid] - tsum;
    rs[i0] = ex; rs[i0 + 1] = ex + v0; rs[i0 + 2] = ex + v0 + v1; rs[i0 + 3] = ex + v0 + v1 + v2;
    __syncthreads();
    for (int i = tid; i < nNodes; i += 256) row_start[nodeBase + i] = lo + rs[i];
    for (int i = tid; i < BNODES; i += 256) deg[i] = 0;
    __syncthreads();
    for (int j = lo + tid; j < hi; j += 256) {
        int2 r = rec[j];
        int dl = r.x >> 18;
        int p = lo + rs[dl] + atomicAdd(&deg[dl], 1);
        colw[p] = make_int2(r.x & 0x3FFFF, r.y);
    }
}

// ---------------- Layer 1 fused: s=A@x; x1=relu(s*W11+x*W21+b1); h2=x1@W1_2 (fp8) ----------------
__global__ void l1_fused_kernel(const float* __restrict__ x,
                                const int* __restrict__ row_start, const int2* __restrict__ colw,
                                const float* __restrict__ W11, const float* __restrict__ W21,
                                const float* __restrict__ b1, const float* __restrict__ W12,
                                float* __restrict__ x1, unsigned char* __restrict__ h2, int N) {
    __shared__ float w1s[CH][CH];
    __shared__ float xs[8][CH + 1];
    int tid = threadIdx.x;  // 256
    for (int t = tid; t < CH * CH; t += 256) w1s[t >> 5][t & 31] = W12[t];
    int ln = tid >> 5, c = tid & 31;
    int node = blockIdx.x * 8 + ln;
    float s = 0.f, xv = 0.f;
    if (node < N) {
        xv = x[node];
        int lo = row_start[node], hi = row_start[node + 1];
        for (int j = lo + c; j < hi; j += 32) {
            int2 cw = colw[j];
            s += __int_as_float(cw.y) * x[cw.x];
        }
    }
    for (int m = 1; m < 32; m <<= 1) s += __shfl_xor(s, m);
    float x1v = 0.f;
    if (node < N) {
        x1v = fmaxf(fmaf(s, W11[c], fmaf(xv, W21[c], b1[c])), 0.f);
        x1[(size_t)node * CH + c] = x1v;
    }
    xs[ln][c] = x1v;
    __syncthreads();
    if (node < N) {
        float a = 0.f;
#pragma unroll
        for (int k = 0; k < CH; k++) a = fmaf(xs[ln][k], w1s[k][c], a);
        h2[(size_t)node * CH + c] = f32_to_fp8(a);
    }
}

// ---------------- Gather: fp8 h in, optional fused next-layer h emit to a SEPARATE buffer ----------------
// xio[n] = relu( sum_j w*h[col] + xio[n]@W2 + b ), in place (own rows only).
// If EMIT_H: hout[n] = (xio_new[n] @ W1next) in fp8; hout MUST NOT alias h.
template <bool EMIT_H>
__global__ void gather_kernel(float* __restrict__ xio, const unsigned char* __restrict__ h,
                              const int* __restrict__ row_start, const int2* __restrict__ colw,
                              const float* __restrict__ W2, const float* __restrict__ b,
                              const float* __restrict__ W1next, unsigned char* __restrict__ hout,
                              int N) {
    __shared__ float w2s[CH][CH];
    __shared__ float w1s[EMIT_H ? CH : 1][CH];
    __shared__ float xs[NT][CH + 1];
    __shared__ int2 cws[CAP];
    int tid = threadIdx.x;  // 256
    int nodeBase = blockIdx.x * NT;

    for (int t = tid; t < CH * CH; t += 256) {
        w2s[t >> 5][t & 31] = W2[t];
        if (EMIT_H) w1s[t >> 5][t & 31] = W1next[t];
    }
    {
        int n = tid >> 5, c = tid & 31;
        for (int p = 0; p < NT / 8; p++) {
            int node = nodeBase + p * 8 + n;
            xs[p * 8 + n][c] = (node < N) ? xio[(size_t)node * CH + c] : 0.f;
        }
    }
    int lo = row_start[min(nodeBase, N)];
    int hi = row_start[min(nodeBase + NT, N)];
    int cnt = min(hi - lo, CAP);
    for (int t = tid; t < cnt; t += 256) cws[t] = colw[lo + t];
    __syncthreads();

    int grp = tid >> 4, l16 = tid & 15;   // 16 groups of 16 lanes
    int c0 = l16 * 2;
#pragma unroll
    for (int rep = 0; rep < NT / 16; rep++) {
        int nloc = rep * 16 + grp;
        int node = nodeBase + nloc;
        if (node < N) {
            int ls = row_start[node], le = row_start[node + 1];
            float a0 = b[c0], a1 = b[c0 + 1];
#pragma unroll
            for (int k = 0; k < CH; k++) {
                float xk = xs[nloc][k];
                float2 wk = *reinterpret_cast<const float2*>(&w2s[k][c0]);
                a0 = fmaf(xk, wk.x, a0);
                a1 = fmaf(xk, wk.y, a1);
            }
            if (le - lo <= cnt) {
                int j = ls;
                for (; j + 4 <= le; j += 4) {
                    int2 e0 = cws[j - lo], e1 = cws[j + 1 - lo], e2 = cws[j + 2 - lo], e3 = cws[j + 3 - lo];
                    unsigned int p0 = *reinterpret_cast<const unsigned short*>(h + (size_t)e0.x * CH + c0);
                    unsigned int p1 = *reinterpret_cast<const unsigned short*>(h + (size_t)e1.x * CH + c0);
                    unsigned int p2 = *reinterpret_cast<const unsigned short*>(h + (size_t)e2.x * CH + c0);
                    unsigned int p3 = *reinterpret_cast<const unsigned short*>(h + (size_t)e3.x * CH + c0);
                    float w0 = __int_as_float(e0.y), w1 = __int_as_float(e1.y);
                    float w2 = __int_as_float(e2.y), w3 = __int_as_float(e3.y);
                    a0 = fmaf(w0, fp8_to_f32(p0 & 0xff), a0); a1 = fmaf(w0, fp8_to_f32(p0 >> 8), a1);
                    a0 = fmaf(w1, fp8_to_f32(p1 & 0xff), a0); a1 = fmaf(w1, fp8_to_f32(p1 >> 8), a1);
                    a0 = fmaf(w2, fp8_to_f32(p2 & 0xff), a0); a1 = fmaf(w2, fp8_to_f32(p2 >> 8), a1);
                    a0 = fmaf(w3, fp8_to_f32(p3 & 0xff), a0); a1 = fmaf(w3, fp8_to_f32(p3 >> 8), a1);
                }
                for (; j < le; j++) {
                    int2 e = cws[j - lo];
                    unsigned int p = *reinterpret_cast<const unsigned short*>(h + (size_t)e.x * CH + c0);
                    float wj = __int_as_float(e.y);
                    a0 = fmaf(wj, fp8_to_f32(p & 0xff), a0); a1 = fmaf(wj, fp8_to_f32(p >> 8), a1);
                }
            } else {
                for (int j = ls; j < le; j++) {
                    int2 e = colw[j];
                    unsigned int p = *reinterpret_cast<const unsigned short*>(h + (size_t)e.x * CH + c0);
                    float wj = __int_as_float(e.y);
                    a0 = fmaf(wj, fp8_to_f32(p & 0xff), a0); a1 = fmaf(wj, fp8_to_f32(p >> 8), a1);
                }
            }
            float r0 = fmaxf(a0, 0.f), r1 = fmaxf(a1, 0.f);
            *reinterpret_cast<float2*>(&xio[(size_t)node * CH + c0]) = make_float2(r0, r1);
            if (EMIT_H) { xs[nloc][c0] = r0; xs[nloc][c0 + 1] = r1; }  // own row, own channels
        }
    }
    if (EMIT_H) {
        __syncthreads();
#pragma unroll
        for (int rep = 0; rep < NT / 16; rep++) {
            int nloc = rep * 16 + grp;
            int node = nodeBase + nloc;
            if (node >= N) continue;
            float a0 = 0.f, a1 = 0.f;
#pragma unroll
            for (int k = 0; k < CH; k++) {
                float xk = xs[nloc][k];
                float2 wk = *reinterpret_cast<const float2*>(&w1s[k][c0]);
                a0 = fmaf(xk, wk.x, a0);
                a1 = fmaf(xk, wk.y, a1);
            }
            unsigned short pk = (unsigned short)f32_to_fp8(a0) |
                                ((unsigned short)f32_to_fp8(a1) << 8);
            *reinterpret_cast<unsigned short*>(hout + (size_t)node * CH + c0) = pk;
        }
    }
}

// seg SORTED: one 64-thread block per graph; fused mean-pool + dense + sigmoid
__global__ void pool_head_kernel(const float* __restrict__ x3, const int* __restrict__ seg,
                                 const float* __restrict__ Wd, const float* __restrict__ bd,
                                 float* __restrict__ out, int N, int G) {
    int g = blockIdx.x;
    int tid = threadIdx.x;  // 64
    int lo = 0, hi = N;
    while (lo < hi) { int mid = (lo + hi) >> 1; if (seg[mid] < g) lo = mid + 1; else hi = mid; }
    int start = lo;
    hi = N;
    while (lo < hi) { int mid = (lo + hi) >> 1; if (seg[mid] < g + 1) lo = mid + 1; else hi = mid; }
    int end = lo;
    int half = tid >> 5, c = tid & 31;
    float s = 0.f;
    for (int n = start + half; n < end; n += 2) s += x3[(size_t)n * CH + c];
    s += __shfl_xor(s, 32);
    float t = s * Wd[c];
    for (int m = 1; m < 32; m <<= 1) t += __shfl_xor(t, m);
    if (tid == 0) {
        float cnt = fmaxf((float)(end - start), 1.f);
        float logit = t / cnt + bd[0];
        out[g] = 1.f / (1.f + expf(-logit));
    }
}

extern "C" void kernel_launch(void* const* d_in, const int* in_sizes, int n_in,
                              void* d_out, int out_size, void* d_ws, size_t ws_size,
                              hipStream_t stream) {
    const float* x        = (const float*)d_in[0];
    const int*   edge_src = (const int*)d_in[1];
    const int*   edge_dst = (const int*)d_in[2];
    const float* edge_w   = (const float*)d_in[3];
    const int*   seg      = (const int*)d_in[4];
    const float* W1_1 = (const float*)d_in[5];
    const float* W2_1 = (const float*)d_in[6];
    const float* b1   = (const float*)d_in[7];
    const float* W1_2 = (const float*)d_in[8];
    const float* W2_2 = (const float*)d_in[9];
    const float* b2   = (const float*)d_in[10];
    const float* W1_3 = (const float*)d_in[11];
    const float* W2_3 = (const float*)d_in[12];
    const float* b3   = (const float*)d_in[13];
    const float* Wd   = (const float*)d_in[14];
    const float* bd   = (const float*)d_in[15];
    float* out = (float*)d_out;

    const int N = in_sizes[0];   // 262144
    const int E = in_sizes[1];   // 4194304
    const int G = out_size;      // 4096
    (void)ws_size; (void)n_in;

    const int nbuk = (N + BNODES - 1) >> BSHIFT;   // 256

    const size_t NB = (size_t)N * CH;
    float*           xbuf      = (float*)d_ws;
    int2*            rec       = (int2*)d_ws;                   // alias: dead before l1_fused
    unsigned char*   h8a       = (unsigned char*)(xbuf + NB);   // fp8 h2 table (8 MB)
    unsigned char*   h8b       = h8a + NB;                      // fp8 h3 table (8 MB) — separate!
    int*             row_start = (int*)(h8b + NB);
    int2*            colw      = (int2*)(row_start + (N + 8));
    int*             bucketCount = (int*)(colw + E);
    int*             bucketStart = bucketCount + MAXBUK;
    int*             bucketTail  = bucketStart + MAXBUK + 4;

    const int BLK = 256;

    // ---- CSR build via two-level bucket sort ----
    hipMemsetAsync(bucketCount, 0, MAXBUK * sizeof(int), stream);
    bucket_hist_kernel<<<512, BLK, 0, stream>>>(edge_dst, bucketCount, E, nbuk);
    bucket_scan_kernel<<<1, BLK, 0, stream>>>(bucketCount, bucketStart, bucketTail, row_start, nbuk, N, E);
    bucket_scatter_kernel<<<(E + P3_CHUNK - 1) / P3_CHUNK, BLK, 0, stream>>>(
        edge_src, edge_dst, edge_w, bucketTail, rec, E, nbuk);
    local_csr_kernel<<<nbuk, BLK, 0, stream>>>(rec, bucketStart, row_start, colw, N);

    // ---- Layer 1 (fused: agg + out + h2 gemm, fp8 h) ----
    l1_fused_kernel<<<(N + 7) / 8, BLK, 0, stream>>>(x, row_start, colw,
                                                     W1_1, W2_1, b1, W1_2, xbuf, h8a, N);
    // ---- Layer 2: reads h8a, emits h3 into h8b (no aliasing) ----
    gather_kernel<true><<<(N + NT - 1) / NT, BLK, 0, stream>>>(xbuf, h8a, row_start, colw,
                                                               W2_2, b2, W1_3, h8b, N);
    // ---- Layer 3: reads h8b ----
    gather_kernel<false><<<(N + NT - 1) / NT, BLK, 0, stream>>>(xbuf, h8b, row_start, colw,
                                                                W2_3, b3, nullptr, nullptr, N);

    // ---- Fused pool + head ----
    pool_head_kernel<<<G, 64, 0, stream>>>(xbuf, seg, Wd, bd, out, N, G);
}